// Round 12
// baseline (173.103 us; speedup 1.0000x reference)
//
#include <hip/hip_runtime.h>
#include <stdint.h>

// ---------------------------------------------------------------------------
// B=4, T=1024, C=1024, H=16, hs=64.
// y = samples @ V (straight-through => forward output IS the Bernoulli sample),
// att_sum = per-row sample count (popcount), att_var == 0 exactly.
// Samples reproduce JAX partitionable threefry bit-exactly:
//   bits[i] = o0 ^ o1 of threefry(fold_in(key(0),42), (0, i)).
// Attention in TWO kernels:
//   A attn_sample: 8704 IDENTICAL blocks (bh x lower-tri (qt,kt) 64x64 tiles).
//     4-WAY INTERLEAVED threefry chains (explicit ILP: the R11 version ran at
//     VGPR=20 -> serialized dep chains; this forces 4 independent states).
//   B attn_pv: y = P@V expanding bits -> bf16 frags (MFMA order identical to
//     the fused version => bit-identical y); att_sum = popcount; att_var = 0.
// ---------------------------------------------------------------------------

#define T_SEQ 1024
#define QKV_LD 3072

typedef __attribute__((ext_vector_type(8))) short bf16x8;
typedef __attribute__((ext_vector_type(4))) float f32x4;
typedef __attribute__((ext_vector_type(4))) unsigned int u32x4;

typedef __attribute__((address_space(3))) uint32_t lds_u32;
typedef __attribute__((address_space(1))) const uint32_t g_u32;

#define ROTL(x, d) __builtin_amdgcn_alignbit((x), (x), 32 - (d))

__device__ __forceinline__ void threefry2x32(uint32_t k0, uint32_t k1,
                                             uint32_t x0, uint32_t x1,
                                             uint32_t &o0, uint32_t &o1) {
  uint32_t ks2 = k0 ^ k1 ^ 0x1BD11BDAu;
#define TF_R4(a, b, c, d)                                                      \
  x0 += x1; x1 = ROTL(x1, a); x1 ^= x0;                                        \
  x0 += x1; x1 = ROTL(x1, b); x1 ^= x0;                                        \
  x0 += x1; x1 = ROTL(x1, c); x1 ^= x0;                                        \
  x0 += x1; x1 = ROTL(x1, d); x1 ^= x0;
  x0 += k0; x1 += k1;
  TF_R4(13, 15, 26, 6)
  x0 += k1; x1 += ks2 + 1u;
  TF_R4(17, 29, 16, 24)
  x0 += ks2; x1 += k0 + 2u;
  TF_R4(13, 15, 26, 6)
  x0 += k0; x1 += k1 + 3u;
  TF_R4(17, 29, 16, 24)
  x0 += k1; x1 += ks2 + 4u;
  TF_R4(13, 15, 26, 6)
  x0 += ks2; x1 += k0 + 5u;
  o0 = x0; o1 = x1;
#undef TF_R4
}

__device__ __forceinline__ unsigned short f2bf(float f) {  // RNE
  uint32_t u = __float_as_uint(f);
  u += 0x7FFFu + ((u >> 16) & 1u);
  return (unsigned short)(u >> 16);
}

// ---------------------------------------------------------------------------
// Fused f32->bf16 conversion of x, w_attn, w_proj (outputs contiguous in ws).
// ---------------------------------------------------------------------------
#define N_X4  1048576   // 4M f32 / 4
#define N_WA4 786432    // 3M / 4
#define N_WP4 262144    // 1M / 4

__global__ __launch_bounds__(256) void cvt3_bf16(const float4* __restrict__ x,
                                                 const float4* __restrict__ wa,
                                                 const float4* __restrict__ wp,
                                                 uint2* __restrict__ out) {
  size_t i = (size_t)blockIdx.x * 256 + threadIdx.x;
  const float4* src;
  size_t off;
  if (i < N_X4) { src = x; off = i; }
  else if (i < N_X4 + N_WA4) { src = wa; off = i - N_X4; }
  else { src = wp; off = i - (N_X4 + N_WA4); }
  float4 v = src[off];
  uint2 o;
  o.x = (uint32_t)f2bf(v.x) | ((uint32_t)f2bf(v.y) << 16);
  o.y = (uint32_t)f2bf(v.z) | ((uint32_t)f2bf(v.w) << 16);
  out[i] = o;
}

// ---------------------------------------------------------------------------
// bf16 MFMA GEMM: C[M,N] = A[M,K] @ B[N,K]^T. 128x128 tile, BK=32, 4 waves.
// m97 structure: global_load_lds width-16 into LINEAR LDS [row][32 bf16].
// ---------------------------------------------------------------------------
template <int OUT_BF16>
__global__ __launch_bounds__(256) void gemm_bf16(const unsigned short* __restrict__ A,
                                                 const unsigned short* __restrict__ B,
                                                 void* __restrict__ Cout,
                                                 int M, int N, int K) {
  __shared__ unsigned short As[128 * 32];  // 8 KB, linear
  __shared__ unsigned short Bs[128 * 32];

  const int t = threadIdx.x;
  const int lane = t & 63, w = t >> 6;
  const int g = lane >> 4, lr = lane & 15;
  const int rw = w >> 1, cw = w & 1;
  const int bm = blockIdx.x * 128, bn = blockIdx.y * 128;

  const unsigned short* Ag = A + (size_t)(bm + 32 * w + (lane >> 2)) * K + 8 * (lane & 3);
  const unsigned short* Bg = B + (size_t)(bn + 32 * w + (lane >> 2)) * K + 8 * (lane & 3);
  lds_u32* Al0 = (lds_u32*)&As[(32 * w) * 32];
  lds_u32* Al1 = (lds_u32*)&As[(32 * w + 16) * 32];
  lds_u32* Bl0 = (lds_u32*)&Bs[(32 * w) * 32];
  lds_u32* Bl1 = (lds_u32*)&Bs[(32 * w + 16) * 32];

  f32x4 acc[4][4];
#pragma unroll
  for (int i = 0; i < 4; ++i)
#pragma unroll
    for (int j = 0; j < 4; ++j) acc[i][j] = (f32x4){0.f, 0.f, 0.f, 0.f};

  for (int k0 = 0; k0 < K; k0 += 32) {
    __syncthreads();
    __builtin_amdgcn_global_load_lds((g_u32*)(const void*)(Ag + k0), Al0, 16, 0, 0);
    __builtin_amdgcn_global_load_lds((g_u32*)(const void*)(Ag + k0 + (size_t)16 * K), Al1, 16, 0, 0);
    __builtin_amdgcn_global_load_lds((g_u32*)(const void*)(Bg + k0), Bl0, 16, 0, 0);
    __builtin_amdgcn_global_load_lds((g_u32*)(const void*)(Bg + k0 + (size_t)16 * K), Bl1, 16, 0, 0);
    __syncthreads();

    bf16x8 af[4], bfr[4];
#pragma unroll
    for (int i = 0; i < 4; ++i)
      af[i] = *(const bf16x8*)&As[(64 * rw + 16 * i + lr) * 32 + 8 * g];
#pragma unroll
    for (int j = 0; j < 4; ++j)
      bfr[j] = *(const bf16x8*)&Bs[(64 * cw + 16 * j + lr) * 32 + 8 * g];
#pragma unroll
    for (int i = 0; i < 4; ++i)
#pragma unroll
      for (int j = 0; j < 4; ++j)
        acc[i][j] = __builtin_amdgcn_mfma_f32_16x16x32_bf16(af[i], bfr[j], acc[i][j], 0, 0, 0);
  }

#pragma unroll
  for (int i = 0; i < 4; ++i)
#pragma unroll
    for (int j = 0; j < 4; ++j)
#pragma unroll
      for (int r = 0; r < 4; ++r) {
        const size_t row = bm + 64 * rw + 16 * i + 4 * g + r;
        const size_t col = bn + 64 * cw + 16 * j + lr;
        if (OUT_BF16)
          ((unsigned short*)Cout)[row * N + col] = f2bf(acc[i][j][r]);
        else
          ((float*)Cout)[row * N + col] = acc[i][j][r];
      }
}

// ---------------------------------------------------------------------------
// Kernel A: score-tile sampler. 8704 identical blocks, 4-way ILP threefry.
// bid -> bh = 8*(bid&7)+((bid>>3)&7) (XCD-affine), id136 = bid>>6,
// qt = QT_OF[id136], kt = id136 - qt(qt+1)/2.
// ---------------------------------------------------------------------------
__constant__ uint8_t QT_OF[136] = {
    0, 1, 1, 2, 2, 2, 3, 3, 3, 3, 4, 4, 4, 4, 4, 5, 5, 5, 5, 5, 5,
    6, 6, 6, 6, 6, 6, 6, 7, 7, 7, 7, 7, 7, 7, 7,
    8, 8, 8, 8, 8, 8, 8, 8, 8, 9, 9, 9, 9, 9, 9, 9, 9, 9, 9,
    10, 10, 10, 10, 10, 10, 10, 10, 10, 10, 10,
    11, 11, 11, 11, 11, 11, 11, 11, 11, 11, 11, 11,
    12, 12, 12, 12, 12, 12, 12, 12, 12, 12, 12, 12, 12,
    13, 13, 13, 13, 13, 13, 13, 13, 13, 13, 13, 13, 13, 13,
    14, 14, 14, 14, 14, 14, 14, 14, 14, 14, 14, 14, 14, 14, 14,
    15, 15, 15, 15, 15, 15, 15, 15, 15, 15, 15, 15, 15, 15, 15, 15};

// 4 interleaved threefry round-quads: steps all 4 states through one round.
#define TFI_STEP(a)                                                            \
  _Pragma("unroll")                                                            \
  for (int j = 0; j < 4; ++j) {                                                \
    X0[j] += X1[j]; X1[j] = ROTL(X1[j], a); X1[j] ^= X0[j];                    \
  }
#define TFI_R4(a, b, c, d) TFI_STEP(a) TFI_STEP(b) TFI_STEP(c) TFI_STEP(d)
#define TFI_INJ(i0, i1)                                                        \
  _Pragma("unroll")                                                            \
  for (int j = 0; j < 4; ++j) { X0[j] += (i0); X1[j] += (i1); }

__global__ __launch_bounds__(256, 8) void attn_sample(const unsigned short* __restrict__ qkv,
                                                      unsigned short* __restrict__ Pbits) {
  __shared__ uint32_t Ks4[64 * 32];  // 8 KB

  const int t = threadIdx.x;
  const int lane = t & 63, w = t >> 6;
  const int g = lane >> 4, lr = lane & 15;
  const int bid = blockIdx.x;                   // 0..8703
  const int bh = 8 * (bid & 7) + ((bid >> 3) & 7);
  const int id = bid >> 6;                      // 0..135
  const int qt = QT_OF[id];
  const int kt = id - ((qt * (qt + 1)) >> 1);
  const int b = bh >> 4, h = bh & 15;
  const int q0 = qt * 64 + 16 * w;
  const int kt64 = kt * 64;
  const bool diag = (kt == qt);

  uint32_t dk0, dk1;  // fold_in(key(0), 42) -- constant-folded at compile time
  threefry2x32(0u, 0u, 0u, 42u, dk0, dk1);
  const uint32_t ks2 = dk0 ^ dk1 ^ 0x1BD11BDAu;

  // ---- stage K tile (coalesced, swizzled) ----
  const unsigned short* kb = qkv + (size_t)(b * T_SEQ + kt64) * QKV_LD + 1024 + h * 64;
  {
    const int r = t >> 2, s4 = t & 3;
    const unsigned short* src = kb + (size_t)r * QKV_LD + 8 * s4;
    u32x4 v0 = *(const u32x4*)(src);
    u32x4 v1 = *(const u32x4*)(src + 32);
    const int sw = (r & 7) << 2;
    *(u32x4*)&Ks4[r * 32 + ((4 * s4) ^ sw)] = v0;
    *(u32x4*)&Ks4[r * 32 + ((4 * s4 + 16) ^ sw)] = v1;
  }
  // ---- Q A-frags direct from global ----
  const unsigned short* qr = qkv + (size_t)(b * T_SEQ + q0 + lr) * QKV_LD + h * 64 + 8 * g;
  const bf16x8 aq0 = *(const bf16x8*)qr;
  const bf16x8 aq1 = *(const bf16x8*)(qr + 32);
  __syncthreads();

  const int swzr = (lr & 7) << 2;
  unsigned short* prow = Pbits + ((size_t)((bh << 10) + q0)) * 64 + kt * 4;

#pragma unroll
  for (int c = 0; c < 4; ++c) {
    bool pred[4] = {false, false, false, false};
    // uniform skip: in a diagonal tile, chunks c>w are fully above the causal
    // boundary (kg_max = 16c+15 < 16w <= qg_min).
    if (!diag || c <= w) {
      const uint32_t* krow = &Ks4[(16 * c + lr) * 32];
      bf16x8 bk0 = *(const bf16x8*)&krow[(4 * g) ^ swzr];
      bf16x8 bk1 = *(const bf16x8*)&krow[(4 * g + 16) ^ swzr];
      f32x4 sa = __builtin_amdgcn_mfma_f32_16x16x32_bf16(aq0, bk0, (f32x4){0.f, 0.f, 0.f, 0.f}, 0, 0, 0);
      sa = __builtin_amdgcn_mfma_f32_16x16x32_bf16(aq1, bk1, sa, 0, 0, 0);

      const int kg = kt64 + 16 * c + lr;
      const uint32_t idxc =
          ((uint32_t)bh << 20) | ((uint32_t)(q0 + 4 * g) << 10) | (uint32_t)kg;

      // e[r] = exp(-s/8) (independent, scheduled alongside the chains)
      float e[4];
#pragma unroll
      for (int r = 0; r < 4; ++r)
        e[r] = __builtin_exp2f(sa[r] * -0.18033688011112042f);

      // ---- 4 interleaved threefry chains (counter = (0, idxc + r*1024)) ----
      uint32_t X0[4], X1[4];
#pragma unroll
      for (int r = 0; r < 4; ++r) { X0[r] = dk0; X1[r] = idxc + ((uint32_t)r << 10) + dk1; }
      TFI_R4(13, 15, 26, 6)
      TFI_INJ(dk1, ks2 + 1u)
      TFI_R4(17, 29, 16, 24)
      TFI_INJ(ks2, dk0 + 2u)
      TFI_R4(13, 15, 26, 6)
      TFI_INJ(dk0, dk1 + 3u)
      TFI_R4(17, 29, 16, 24)
      TFI_INJ(dk1, ks2 + 4u)
      TFI_R4(13, 15, 26, 6)
      TFI_INJ(ks2, dk0 + 5u)

#pragma unroll
      for (int r = 0; r < 4; ++r) {
        const int qg = q0 + 4 * g + r;
        float u = __uint_as_float(0x3F800000u | ((X0[r] ^ X1[r]) >> 9)) - 1.0f;
        // u < 1/(1+e) <=> u(1+e) < 1 ; branchless causal mask (off-diag: always true)
        pred[r] = (fmaf(u, e[r], u) < 1.0f) & (kg <= qg);
      }
    }
#pragma unroll
    for (int r = 0; r < 4; ++r) {
      unsigned long long m = __ballot(pred[r]);
      if (lr == 0)  // 4 lanes (one per g) store their row's 16 bits
        prow[(size_t)(4 * g + r) * 64 + c] = (unsigned short)((m >> (16 * g)) & 0xFFFFu);
    }
  }
}

// ---------------------------------------------------------------------------
// Kernel B: PV from bitmask. Block = (bh, qt); 1024 blocks x 4 waves.
// ---------------------------------------------------------------------------
__global__ __launch_bounds__(256) void attn_pv(const unsigned short* __restrict__ qkv,
                                               const unsigned short* __restrict__ Pbits,
                                               unsigned short* __restrict__ yatt,
                                               float* __restrict__ att_sum,
                                               float* __restrict__ att_var) {
  __shared__ uint32_t Vt4[64 * 32];  // 8 KB

  const int t = threadIdx.x;
  const int lane = t & 63, w = t >> 6;
  const int g = lane >> 4, lr = lane & 15;
  const int bid = blockIdx.x;                   // 0..1023
  const int bh = 8 * (bid & 7) + ((bid >> 3) & 7);
  const int qt = 15 - (bid >> 6);               // heavy-first
  const int b = bh >> 4, h = bh & 15;
  const int q0 = qt * 64 + 16 * w;

  const int swzr = (lr & 7) << 2;
  const unsigned short* prow = Pbits + ((size_t)((bh << 10) + q0 + lr)) * 64;

  f32x4 yacc[4];
#pragma unroll
  for (int c = 0; c < 4; ++c) yacc[c] = (f32x4){0.f, 0.f, 0.f, 0.f};
  uint32_t rs = 0;

#pragma unroll 1
  for (int kt = 0; kt <= qt; ++kt) {
    __syncthreads();  // prev Vt reads complete
    // ---- stage V transposed: Vt[d][k] ----
    {
      const int k2 = 2 * (t & 31), d0 = 8 * (t >> 5);
      const unsigned short* vsrc =
          qkv + (size_t)(b * T_SEQ + kt * 64 + k2) * QKV_LD + 2048 + h * 64 + d0;
      union { u32x4 v; unsigned short us[8]; } va, vb2;
      va.v = *(const u32x4*)(vsrc);
      vb2.v = *(const u32x4*)(vsrc + QKV_LD);
#pragma unroll
      for (int jj = 0; jj < 8; ++jj) {
        uint32_t pw = (uint32_t)va.us[jj] | ((uint32_t)vb2.us[jj] << 16);
        Vt4[(d0 + jj) * 32 + ((t & 31) ^ ((jj & 7) << 2))] = pw;
      }
    }
    __syncthreads();

    // ---- this row's 64 sample bits for the k-step ----
    const uint64_t bits = *(const uint64_t*)(prow + kt * 4);
    rs += (uint32_t)__popcll(bits);  // same value across g; only g==0 writes

    // ---- Y += P @ V (bit-expand A-frags; order identical to fused) ----
#pragma unroll
    for (int ks = 0; ks < 2; ++ks) {
      const uint32_t byte = (uint32_t)(bits >> (32 * ks + 8 * g)) & 0xFFu;
      union { uint32_t u[4]; bf16x8 v; } pa;
#pragma unroll
      for (int j = 0; j < 4; ++j) {
        pa.u[j] = ((byte >> (2 * j)) & 1u ? 0x3F80u : 0u) |
                  ((byte >> (2 * j + 1)) & 1u ? 0x3F800000u : 0u);
      }
#pragma unroll
      for (int c = 0; c < 4; ++c) {
        bf16x8 vb = *(const bf16x8*)&Vt4[(16 * c + lr) * 32 + ((4 * g + 16 * ks) ^ swzr)];
        yacc[c] = __builtin_amdgcn_mfma_f32_16x16x32_bf16(pa.v, vb, yacc[c], 0, 0, 0);
      }
    }
  }

  // ---- epilogue: yatt (bf16), att_sum, att_var ----
  const size_t yb = (size_t)(b * T_SEQ + q0) * 1024 + h * 64;
#pragma unroll
  for (int c = 0; c < 4; ++c)
#pragma unroll
    for (int r = 0; r < 4; ++r)
      yatt[yb + (size_t)(4 * g + r) * 1024 + 16 * c + lr] = f2bf(yacc[c][r]);

  if (g == 0) att_sum[(size_t)bh * T_SEQ + q0 + lr] = (float)rs;
  if (lane < 16) att_var[(size_t)bh * T_SEQ + q0 + lane] = 0.f;  // s*(1-s)==0
}

extern "C" void kernel_launch(void* const* d_in, const int* in_sizes, int n_in,
                              void* d_out, int out_size, void* d_ws, size_t ws_size,
                              hipStream_t stream) {
  (void)in_sizes; (void)n_in; (void)out_size; (void)ws_size;
  const float* x      = (const float*)d_in[0];  // [4,1024,1024]
  const float* w_attn = (const float*)d_in[1];  // [3072,1024]
  const float* w_proj = (const float*)d_in[2];  // [1024,1024]

  float* y_out      = (float*)d_out;                    // [4,1024,1024] f32
  float* attsum_out = y_out + (size_t)4 * 1024 * 1024;  // [4,16,1024]
  float* attvar_out = attsum_out + (size_t)4 * 16 * 1024;

  unsigned short* ws_us = (unsigned short*)d_ws;
  unsigned short* x_bf    = ws_us;                             // 4M elems
  unsigned short* wa_bf   = x_bf + (size_t)4 * 1024 * 1024;    // 3M
  unsigned short* wp_bf   = wa_bf + (size_t)3 * 1024 * 1024;   // 1M
  unsigned short* qkv_bf  = wp_bf + (size_t)1024 * 1024;       // 12M
  unsigned short* yatt_bf = qkv_bf + (size_t)4096 * 3072;      // 4M
  unsigned short* pbits   = yatt_bf + (size_t)4096 * 1024;     // 4M u16 = 8MB

  dim3 blk(256);
  cvt3_bf16<<<dim3(8192), blk, 0, stream>>>((const float4*)x, (const float4*)w_attn,
                                            (const float4*)w_proj, (uint2*)x_bf);
  gemm_bf16<1><<<dim3(32, 24), blk, 0, stream>>>(x_bf, wa_bf, (void*)qkv_bf, 4096, 3072, 1024);
  attn_sample<<<dim3(8704), blk, 0, stream>>>(qkv_bf, pbits);
  attn_pv<<<dim3(1024), blk, 0, stream>>>(qkv_bf, pbits, yatt_bf, attsum_out, attvar_out);
  gemm_bf16<0><<<dim3(32, 8), blk, 0, stream>>>(yatt_bf, wp_bf, (void*)y_out, 4096, 1024, 1024);
}

// Round 13
// 169.720 us; speedup vs baseline: 1.0199x; 1.0199x over previous
//
#include <hip/hip_runtime.h>
#include <stdint.h>

// ---------------------------------------------------------------------------
// B=4, T=1024, C=1024, H=16, hs=64.
// y = samples @ V (straight-through => forward output IS the Bernoulli sample),
// att_sum = per-row sample count (popcount), att_var == 0 exactly.
// Samples reproduce JAX partitionable threefry bit-exactly:
//   bits[i] = o0 ^ o1 of threefry(fold_in(key(0),42), (0, i)).
// Attention in TWO kernels:
//   A attn_sample: 8704 IDENTICAL blocks (bh x lower-tri (qt,kt) 64x64 tiles).
//     Causal mask applied on SALU to the ballot (not per-sample VALU).
//   B attn_pv: diagonal-PAIRED blocks (uniform 17 V-stages); y = P@V from the
//     bitmask (MFMA order identical to fused => bit-identical y).
// ---------------------------------------------------------------------------

#define T_SEQ 1024
#define QKV_LD 3072

typedef __attribute__((ext_vector_type(8))) short bf16x8;
typedef __attribute__((ext_vector_type(4))) float f32x4;
typedef __attribute__((ext_vector_type(4))) unsigned int u32x4;

typedef __attribute__((address_space(3))) uint32_t lds_u32;
typedef __attribute__((address_space(1))) const uint32_t g_u32;

#define ROTL(x, d) __builtin_amdgcn_alignbit((x), (x), 32 - (d))

__device__ __forceinline__ void threefry2x32(uint32_t k0, uint32_t k1,
                                             uint32_t x0, uint32_t x1,
                                             uint32_t &o0, uint32_t &o1) {
  uint32_t ks2 = k0 ^ k1 ^ 0x1BD11BDAu;
#define TF_R4(a, b, c, d)                                                      \
  x0 += x1; x1 = ROTL(x1, a); x1 ^= x0;                                        \
  x0 += x1; x1 = ROTL(x1, b); x1 ^= x0;                                        \
  x0 += x1; x1 = ROTL(x1, c); x1 ^= x0;                                        \
  x0 += x1; x1 = ROTL(x1, d); x1 ^= x0;
  x0 += k0; x1 += k1;
  TF_R4(13, 15, 26, 6)
  x0 += k1; x1 += ks2 + 1u;
  TF_R4(17, 29, 16, 24)
  x0 += ks2; x1 += k0 + 2u;
  TF_R4(13, 15, 26, 6)
  x0 += k0; x1 += k1 + 3u;
  TF_R4(17, 29, 16, 24)
  x0 += k1; x1 += ks2 + 4u;
  TF_R4(13, 15, 26, 6)
  x0 += ks2; x1 += k0 + 5u;
  o0 = x0; o1 = x1;
#undef TF_R4
}

__device__ __forceinline__ unsigned short f2bf(float f) {  // RNE
  uint32_t u = __float_as_uint(f);
  u += 0x7FFFu + ((u >> 16) & 1u);
  return (unsigned short)(u >> 16);
}

// ---------------------------------------------------------------------------
// Fused f32->bf16 conversion of x, w_attn, w_proj (outputs contiguous in ws).
// ---------------------------------------------------------------------------
#define N_X4  1048576   // 4M f32 / 4
#define N_WA4 786432    // 3M / 4
#define N_WP4 262144    // 1M / 4

__global__ __launch_bounds__(256) void cvt3_bf16(const float4* __restrict__ x,
                                                 const float4* __restrict__ wa,
                                                 const float4* __restrict__ wp,
                                                 uint2* __restrict__ out) {
  size_t i = (size_t)blockIdx.x * 256 + threadIdx.x;
  const float4* src;
  size_t off;
  if (i < N_X4) { src = x; off = i; }
  else if (i < N_X4 + N_WA4) { src = wa; off = i - N_X4; }
  else { src = wp; off = i - (N_X4 + N_WA4); }
  float4 v = src[off];
  uint2 o;
  o.x = (uint32_t)f2bf(v.x) | ((uint32_t)f2bf(v.y) << 16);
  o.y = (uint32_t)f2bf(v.z) | ((uint32_t)f2bf(v.w) << 16);
  out[i] = o;
}

// ---------------------------------------------------------------------------
// bf16 MFMA GEMM: C[M,N] = A[M,K] @ B[N,K]^T. 128x128 tile, BK=32, 4 waves.
// m97 structure: global_load_lds width-16 into LINEAR LDS [row][32 bf16].
// ---------------------------------------------------------------------------
template <int OUT_BF16>
__global__ __launch_bounds__(256) void gemm_bf16(const unsigned short* __restrict__ A,
                                                 const unsigned short* __restrict__ B,
                                                 void* __restrict__ Cout,
                                                 int M, int N, int K) {
  __shared__ unsigned short As[128 * 32];  // 8 KB, linear
  __shared__ unsigned short Bs[128 * 32];

  const int t = threadIdx.x;
  const int lane = t & 63, w = t >> 6;
  const int g = lane >> 4, lr = lane & 15;
  const int rw = w >> 1, cw = w & 1;
  const int bm = blockIdx.x * 128, bn = blockIdx.y * 128;

  const unsigned short* Ag = A + (size_t)(bm + 32 * w + (lane >> 2)) * K + 8 * (lane & 3);
  const unsigned short* Bg = B + (size_t)(bn + 32 * w + (lane >> 2)) * K + 8 * (lane & 3);
  lds_u32* Al0 = (lds_u32*)&As[(32 * w) * 32];
  lds_u32* Al1 = (lds_u32*)&As[(32 * w + 16) * 32];
  lds_u32* Bl0 = (lds_u32*)&Bs[(32 * w) * 32];
  lds_u32* Bl1 = (lds_u32*)&Bs[(32 * w + 16) * 32];

  f32x4 acc[4][4];
#pragma unroll
  for (int i = 0; i < 4; ++i)
#pragma unroll
    for (int j = 0; j < 4; ++j) acc[i][j] = (f32x4){0.f, 0.f, 0.f, 0.f};

  for (int k0 = 0; k0 < K; k0 += 32) {
    __syncthreads();
    __builtin_amdgcn_global_load_lds((g_u32*)(const void*)(Ag + k0), Al0, 16, 0, 0);
    __builtin_amdgcn_global_load_lds((g_u32*)(const void*)(Ag + k0 + (size_t)16 * K), Al1, 16, 0, 0);
    __builtin_amdgcn_global_load_lds((g_u32*)(const void*)(Bg + k0), Bl0, 16, 0, 0);
    __builtin_amdgcn_global_load_lds((g_u32*)(const void*)(Bg + k0 + (size_t)16 * K), Bl1, 16, 0, 0);
    __syncthreads();

    bf16x8 af[4], bfr[4];
#pragma unroll
    for (int i = 0; i < 4; ++i)
      af[i] = *(const bf16x8*)&As[(64 * rw + 16 * i + lr) * 32 + 8 * g];
#pragma unroll
    for (int j = 0; j < 4; ++j)
      bfr[j] = *(const bf16x8*)&Bs[(64 * cw + 16 * j + lr) * 32 + 8 * g];
#pragma unroll
    for (int i = 0; i < 4; ++i)
#pragma unroll
      for (int j = 0; j < 4; ++j)
        acc[i][j] = __builtin_amdgcn_mfma_f32_16x16x32_bf16(af[i], bfr[j], acc[i][j], 0, 0, 0);
  }

#pragma unroll
  for (int i = 0; i < 4; ++i)
#pragma unroll
    for (int j = 0; j < 4; ++j)
#pragma unroll
      for (int r = 0; r < 4; ++r) {
        const size_t row = bm + 64 * rw + 16 * i + 4 * g + r;
        const size_t col = bn + 64 * cw + 16 * j + lr;
        if (OUT_BF16)
          ((unsigned short*)Cout)[row * N + col] = f2bf(acc[i][j][r]);
        else
          ((float*)Cout)[row * N + col] = acc[i][j][r];
      }
}

// ---------------------------------------------------------------------------
// Kernel A: score-tile sampler. 8704 identical blocks.
// bid -> bh = 8*(bid&7)+((bid>>3)&7) (XCD-affine), id136 = bid>>6,
// qt = QT_OF[id136], kt = id136 - qt(qt+1)/2.
// Causal mask: SALU s_and on the 64-bit ballot (diag tiles only).
// ---------------------------------------------------------------------------
__constant__ uint8_t QT_OF[136] = {
    0, 1, 1, 2, 2, 2, 3, 3, 3, 3, 4, 4, 4, 4, 4, 5, 5, 5, 5, 5, 5,
    6, 6, 6, 6, 6, 6, 6, 7, 7, 7, 7, 7, 7, 7, 7,
    8, 8, 8, 8, 8, 8, 8, 8, 8, 9, 9, 9, 9, 9, 9, 9, 9, 9, 9,
    10, 10, 10, 10, 10, 10, 10, 10, 10, 10, 10,
    11, 11, 11, 11, 11, 11, 11, 11, 11, 11, 11, 11,
    12, 12, 12, 12, 12, 12, 12, 12, 12, 12, 12, 12, 12,
    13, 13, 13, 13, 13, 13, 13, 13, 13, 13, 13, 13, 13, 13,
    14, 14, 14, 14, 14, 14, 14, 14, 14, 14, 14, 14, 14, 14, 14,
    15, 15, 15, 15, 15, 15, 15, 15, 15, 15, 15, 15, 15, 15, 15, 15};

__global__ __launch_bounds__(256, 8) void attn_sample(const unsigned short* __restrict__ qkv,
                                                      unsigned short* __restrict__ Pbits) {
  __shared__ uint32_t Ks4[64 * 32];  // 8 KB

  const int t = threadIdx.x;
  const int lane = t & 63, w = t >> 6;
  const int g = lane >> 4, lr = lane & 15;
  const int bid = blockIdx.x;                   // 0..8703
  const int bh = 8 * (bid & 7) + ((bid >> 3) & 7);
  const int id = bid >> 6;                      // 0..135
  const int qt = QT_OF[id];
  const int kt = id - ((qt * (qt + 1)) >> 1);
  const int b = bh >> 4, h = bh & 15;
  const int q0 = qt * 64 + 16 * w;
  const int kt64 = kt * 64;
  const bool diag = (kt == qt);
  const int ws = __builtin_amdgcn_readfirstlane(w);  // wave id -> SGPR

  uint32_t dk0, dk1;  // fold_in(key(0), 42) -- constant-folded at compile time
  threefry2x32(0u, 0u, 0u, 42u, dk0, dk1);
  const uint32_t ks2 = dk0 ^ dk1 ^ 0x1BD11BDAu;

  // ---- stage K tile (coalesced, swizzled) ----
  const unsigned short* kb = qkv + (size_t)(b * T_SEQ + kt64) * QKV_LD + 1024 + h * 64;
  {
    const int r = t >> 2, s4 = t & 3;
    const unsigned short* src = kb + (size_t)r * QKV_LD + 8 * s4;
    u32x4 v0 = *(const u32x4*)(src);
    u32x4 v1 = *(const u32x4*)(src + 32);
    const int sw = (r & 7) << 2;
    *(u32x4*)&Ks4[r * 32 + ((4 * s4) ^ sw)] = v0;
    *(u32x4*)&Ks4[r * 32 + ((4 * s4 + 16) ^ sw)] = v1;
  }
  // ---- Q A-frags direct from global ----
  const unsigned short* qr = qkv + (size_t)(b * T_SEQ + q0 + lr) * QKV_LD + h * 64 + 8 * g;
  const bf16x8 aq0 = *(const bf16x8*)qr;
  const bf16x8 aq1 = *(const bf16x8*)(qr + 32);
  __syncthreads();

  const int swzr = (lr & 7) << 2;
  unsigned short* prow = Pbits + ((size_t)((bh << 10) + q0)) * 64 + kt * 4;

// 4 interleaved threefry round-quads over X0[4], X1[4].
#define TFI_STEP(a)                                                            \
  _Pragma("unroll")                                                            \
  for (int j = 0; j < 4; ++j) {                                                \
    X0[j] += X1[j]; X1[j] = ROTL(X1[j], a); X1[j] ^= X0[j];                    \
  }
#define TFI_R4(a, b, c, d) TFI_STEP(a) TFI_STEP(b) TFI_STEP(c) TFI_STEP(d)
#define TFI_INJ(i0, i1)                                                        \
  _Pragma("unroll")                                                            \
  for (int j = 0; j < 4; ++j) { X0[j] += (i0); X1[j] += (i1); }

#pragma unroll
  for (int c = 0; c < 4; ++c) {
    // uniform skip: diagonal tile chunks c>w are fully above the causal bound.
    if (!diag || c <= ws) {
      const uint32_t* krow = &Ks4[(16 * c + lr) * 32];
      bf16x8 bk0 = *(const bf16x8*)&krow[(4 * g) ^ swzr];
      bf16x8 bk1 = *(const bf16x8*)&krow[(4 * g + 16) ^ swzr];
      f32x4 sa = __builtin_amdgcn_mfma_f32_16x16x32_bf16(aq0, bk0, (f32x4){0.f, 0.f, 0.f, 0.f}, 0, 0, 0);
      sa = __builtin_amdgcn_mfma_f32_16x16x32_bf16(aq1, bk1, sa, 0, 0, 0);

      const int kg = kt64 + 16 * c + lr;
      const uint32_t idxc =
          ((uint32_t)bh << 20) | ((uint32_t)(q0 + 4 * g) << 10) | (uint32_t)kg;

      float e[4];
#pragma unroll
      for (int r = 0; r < 4; ++r)
        e[r] = __builtin_exp2f(sa[r] * -0.18033688011112042f);

      uint32_t X0[4], X1[4];
#pragma unroll
      for (int r = 0; r < 4; ++r) { X0[r] = dk0; X1[r] = idxc + ((uint32_t)r << 10) + dk1; }
      TFI_R4(13, 15, 26, 6)
      TFI_INJ(dk1, ks2 + 1u)
      TFI_R4(17, 29, 16, 24)
      TFI_INJ(ks2, dk0 + 2u)
      TFI_R4(13, 15, 26, 6)
      TFI_INJ(dk0, dk1 + 3u)
      TFI_R4(17, 29, 16, 24)
      TFI_INJ(dk1, ks2 + 4u)
      TFI_R4(13, 15, 26, 6)
      TFI_INJ(ks2, dk0 + 5u)

#pragma unroll
      for (int r = 0; r < 4; ++r) {
        float u = __uint_as_float(0x3F800000u | ((X0[r] ^ X1[r]) >> 9)) - 1.0f;
        // u < 1/(1+e)  <=>  u(1+e) < 1  (causal handled on SALU below)
        unsigned long long m = __ballot(fmaf(u, e[r], u) < 1.0f);
        if (diag) {
          // causal mask for (r,c): lane (g,lr) passes iff lr <= 16(w-c)+4g+r.
          const int d = 16 * (ws - c) + r;  // >= 0 in executed chunks
          unsigned long long cm = 0ull;
#pragma unroll
          for (int gg = 0; gg < 4; ++gg) {
            const int thr = d + 4 * gg;
            const uint32_t pc = (thr >= 15) ? 0xFFFFu : ((2u << thr) - 1u);
            cm |= (unsigned long long)pc << (16 * gg);
          }
          m &= cm;
        }
        if (lr == 0)  // 4 lanes (one per g) store their row's 16 bits
          prow[(size_t)(4 * g + r) * 64 + c] = (unsigned short)(m >> (16 * g));
      }
    } else {
#pragma unroll
      for (int r = 0; r < 4; ++r)
        if (lr == 0) prow[(size_t)(4 * g + r) * 64 + c] = 0;
    }
  }
#undef TFI_STEP
#undef TFI_R4
#undef TFI_INJ
}

// ---------------------------------------------------------------------------
// Kernel B: PV from bitmask, diagonal-paired. 512 blocks x 4 waves.
// Block (bh, p): q-tiles {15-p, p} sequentially -> uniform 17 V-stages.
// ---------------------------------------------------------------------------
__global__ __launch_bounds__(256) void attn_pv(const unsigned short* __restrict__ qkv,
                                               const unsigned short* __restrict__ Pbits,
                                               unsigned short* __restrict__ yatt,
                                               float* __restrict__ att_sum,
                                               float* __restrict__ att_var) {
  __shared__ uint32_t Vt4[64 * 32];  // 8 KB

  const int t = threadIdx.x;
  const int lane = t & 63, w = t >> 6;
  const int g = lane >> 4, lr = lane & 15;
  const int bid = blockIdx.x;                   // 0..511
  const int bh = 8 * (bid & 7) + ((bid >> 3) & 7);
  const int p = bid >> 6;                       // 0..7
  const int b = bh >> 4, h = bh & 15;
  const int swzr = (lr & 7) << 2;

#pragma unroll 1
  for (int half = 0; half < 2; ++half) {
    const int qt = half ? p : 15 - p;
    const int q0 = qt * 64 + 16 * w;
    const unsigned short* prow = Pbits + ((size_t)((bh << 10) + q0 + lr)) * 64;

    f32x4 yacc[4];
#pragma unroll
    for (int c = 0; c < 4; ++c) yacc[c] = (f32x4){0.f, 0.f, 0.f, 0.f};
    uint32_t rs = 0;

#pragma unroll 1
    for (int kt = 0; kt <= qt; ++kt) {
      __syncthreads();  // prev Vt reads complete (incl. across halves)
      // ---- stage V transposed: Vt[d][k] ----
      {
        const int k2 = 2 * (t & 31), d0 = 8 * (t >> 5);
        const unsigned short* vsrc =
            qkv + (size_t)(b * T_SEQ + kt * 64 + k2) * QKV_LD + 2048 + h * 64 + d0;
        union { u32x4 v; unsigned short us[8]; } va, vb2;
        va.v = *(const u32x4*)(vsrc);
        vb2.v = *(const u32x4*)(vsrc + QKV_LD);
#pragma unroll
        for (int jj = 0; jj < 8; ++jj) {
          uint32_t pw = (uint32_t)va.us[jj] | ((uint32_t)vb2.us[jj] << 16);
          Vt4[(d0 + jj) * 32 + ((t & 31) ^ ((jj & 7) << 2))] = pw;
        }
      }
      __syncthreads();

      // ---- this row's 64 sample bits for the k-step ----
      const uint64_t bits = *(const uint64_t*)(prow + kt * 4);
      rs += (uint32_t)__popcll(bits);

      // ---- Y += P @ V (bit-expand A-frags; order identical to fused) ----
#pragma unroll
      for (int ks = 0; ks < 2; ++ks) {
        const uint32_t byte = (uint32_t)(bits >> (32 * ks + 8 * g)) & 0xFFu;
        union { uint32_t u[4]; bf16x8 v; } pa;
#pragma unroll
        for (int j = 0; j < 4; ++j) {
          pa.u[j] = ((byte >> (2 * j)) & 1u ? 0x3F80u : 0u) |
                    ((byte >> (2 * j + 1)) & 1u ? 0x3F800000u : 0u);
        }
#pragma unroll
        for (int c = 0; c < 4; ++c) {
          bf16x8 vb = *(const bf16x8*)&Vt4[(16 * c + lr) * 32 + ((4 * g + 16 * ks) ^ swzr)];
          yacc[c] = __builtin_amdgcn_mfma_f32_16x16x32_bf16(pa.v, vb, yacc[c], 0, 0, 0);
        }
      }
    }

    // ---- half epilogue: yatt (bf16), att_sum, att_var ----
    const size_t yb = (size_t)(b * T_SEQ + q0) * 1024 + h * 64;
#pragma unroll
    for (int c = 0; c < 4; ++c)
#pragma unroll
      for (int r = 0; r < 4; ++r)
        yatt[yb + (size_t)(4 * g + r) * 1024 + 16 * c + lr] = f2bf(yacc[c][r]);

    if (g == 0) att_sum[(size_t)bh * T_SEQ + q0 + lr] = (float)rs;
    if (lane < 16) att_var[(size_t)bh * T_SEQ + q0 + lane] = 0.f;  // s*(1-s)==0
  }
}

extern "C" void kernel_launch(void* const* d_in, const int* in_sizes, int n_in,
                              void* d_out, int out_size, void* d_ws, size_t ws_size,
                              hipStream_t stream) {
  (void)in_sizes; (void)n_in; (void)out_size; (void)ws_size;
  const float* x      = (const float*)d_in[0];  // [4,1024,1024]
  const float* w_attn = (const float*)d_in[1];  // [3072,1024]
  const float* w_proj = (const float*)d_in[2];  // [1024,1024]

  float* y_out      = (float*)d_out;                    // [4,1024,1024] f32
  float* attsum_out = y_out + (size_t)4 * 1024 * 1024;  // [4,16,1024]
  float* attvar_out = attsum_out + (size_t)4 * 16 * 1024;

  unsigned short* ws_us = (unsigned short*)d_ws;
  unsigned short* x_bf    = ws_us;                             // 4M elems
  unsigned short* wa_bf   = x_bf + (size_t)4 * 1024 * 1024;    // 3M
  unsigned short* wp_bf   = wa_bf + (size_t)3 * 1024 * 1024;   // 1M
  unsigned short* qkv_bf  = wp_bf + (size_t)1024 * 1024;       // 12M
  unsigned short* yatt_bf = qkv_bf + (size_t)4096 * 3072;      // 4M
  unsigned short* pbits   = yatt_bf + (size_t)4096 * 1024;     // 4M u16 = 8MB

  dim3 blk(256);
  cvt3_bf16<<<dim3(8192), blk, 0, stream>>>((const float4*)x, (const float4*)w_attn,
                                            (const float4*)w_proj, (uint2*)x_bf);
  gemm_bf16<1><<<dim3(32, 24), blk, 0, stream>>>(x_bf, wa_bf, (void*)qkv_bf, 4096, 3072, 1024);
  attn_sample<<<dim3(8704), blk, 0, stream>>>(qkv_bf, pbits);
  attn_pv<<<dim3(512), blk, 0, stream>>>(qkv_bf, pbits, yatt_bf, attsum_out, attvar_out);
  gemm_bf16<0><<<dim3(32, 8), blk, 0, stream>>>(yatt_bf, wp_bf, (void*)y_out, 4096, 1024, 1024);
}